// Round 11
// baseline (556.185 us; speedup 1.0000x reference)
//
#include <hip/hip_runtime.h>
#include <hip/hip_bf16.h>
#include <math.h>

#define Sdim 2048
#define Bdim 2
#define Ddim 768
#define Hdim 12
#define DHdim 64
#define Ldim 2
#define Cdim 128
#define NCdim 16
#define FFdim 3072
#define Gdim 17
#define NSEPd 16
#define HIDd 100
#define NCLSd 7
#define SEPID 2
#define MROWS (Bdim*Sdim)
#define QKVS 2304
#define MNSZ (MROWS*Ddim)
#define NLOC (NCdim*Hdim*Bdim)
#define NGP  (8*Hdim*Bdim)

typedef __bf16 bf16_t;
typedef bf16_t bf16x8 __attribute__((ext_vector_type(8)));
typedef float f32x4 __attribute__((ext_vector_type(4)));
typedef ushort ushort8v __attribute__((ext_vector_type(8)));

__device__ __forceinline__ ushort f2bf(float f) {
    union { float f; unsigned u; } a; a.f = f;
    unsigned u = a.u;
    unsigned r = (u + 0x7fffu + ((u >> 16) & 1u)) >> 16;
    return (ushort)r;
}
__device__ __forceinline__ float bf2f(ushort h) {
    union { unsigned u; float f; } a; a.u = ((unsigned)h) << 16;
    return a.f;
}
__device__ __forceinline__ void gload16(const ushort* g, ushort* l) {
    __builtin_amdgcn_global_load_lds(
        (const __attribute__((address_space(1))) void*)g,
        (__attribute__((address_space(3))) void*)l, 16, 0, 0);
}

// ---------------- sep finding + bias concat ----------------
__global__ __launch_bounds__(1024) void k_findsep(const int* __restrict__ ids,
        int* __restrict__ glob, int* __restrict__ isg,
        const float* __restrict__ bq, const float* __restrict__ bk,
        const float* __restrict__ bv, float* __restrict__ bqkv) {
    __shared__ unsigned long long mw[32];
    __shared__ int pfx[32];
    int t = threadIdx.x;
    int flg[2];
    #pragma unroll
    for (int pass = 0; pass < 2; ++pass) {
        int p = pass * 1024 + t;
        int f = (ids[p] == SEPID);
        flg[pass] = f;
        unsigned long long m = __ballot(f);
        if ((t & 63) == 0) mw[pass * 16 + (t >> 6)] = m;
    }
    __syncthreads();
    if (t == 0) {
        int c = 0;
        #pragma unroll
        for (int i = 0; i < 32; ++i) { pfx[i] = c; c += __popcll(mw[i]); }
        glob[0] = 0;
    }
    __syncthreads();
    #pragma unroll
    for (int pass = 0; pass < 2; ++pass) {
        int p = pass * 1024 + t;
        int w = pass * 16 + (t >> 6);
        int lane = t & 63;
        int rank = pfx[w] + __popcll(mw[w] & ((1ull << lane) - 1ull));
        int ig = 0;
        if (flg[pass] && rank < NSEPd) { glob[rank + 1] = p; ig = 1; }
        if (p == 0) ig = 1;
        isg[p] = ig;
    }
    for (int idx = t; idx < Ldim * QKVS; idx += 1024) {
        int l = idx / QKVS, i = idx % QKVS;
        float v = (i < Ddim) ? bq[l * Ddim + i]
                : (i < 2 * Ddim) ? bk[l * Ddim + i - Ddim]
                : bv[l * Ddim + i - 2 * Ddim];
        bqkv[idx] = v;
    }
}

// ---------------- merged prologue: weight transposes + embedding+LN ----------------
__global__ __launch_bounds__(256) void k_prolog(
        const float* __restrict__ Wq, const float* __restrict__ Wk,
        const float* __restrict__ Wv, const float* __restrict__ Wo,
        const float* __restrict__ W1, const float* __restrict__ W2,
        ushort* __restrict__ wts,
        const int* __restrict__ ids, const float* __restrict__ tok,
        const float* __restrict__ pos, const float* __restrict__ lng,
        const float* __restrict__ lnb, float* __restrict__ x,
        ushort* __restrict__ xb) {
    __shared__ float ts[64][65];
    int bid = blockIdx.x;
    int t = threadIdx.x;
    if (bid < 3456) {
        const size_t WSMALL = (size_t)Ddim * Ddim;
        const size_t WBIG   = (size_t)Ddim * FFdim;
        const size_t WL     = 4 * WSMALL + 2 * WBIG;
        int l = bid / 1728, r = bid % 1728;
        const float* src; ushort* dst; int K, N, tile;
        ushort* base = wts + (size_t)l * WL;
        if (r < 576) {
            int w = r / 144; tile = r % 144; K = Ddim; N = Ddim;
            src = (w == 0 ? Wq : w == 1 ? Wk : w == 2 ? Wv : Wo) + (size_t)l * WSMALL;
            dst = base + (size_t)w * WSMALL;
        } else if (r < 1152) {
            tile = r - 576; K = Ddim; N = FFdim;
            src = W1 + (size_t)l * WBIG; dst = base + 4 * WSMALL;
        } else {
            tile = r - 1152; K = FFdim; N = Ddim;
            src = W2 + (size_t)l * WBIG; dst = base + 4 * WSMALL + WBIG;
        }
        int ntn = N / 64;
        int bn = (tile % ntn) * 64, bk = (tile / ntn) * 64;
        int rx = t & 63, ry = t >> 6;
        #pragma unroll
        for (int i = 0; i < 16; ++i) {
            int row = ry * 16 + i;
            ts[row][rx] = src[(size_t)(bk + row) * N + bn + rx];
        }
        __syncthreads();
        int wr = t >> 4;
        int k0 = (t & 15) * 4;
        #pragma unroll
        for (int pass = 0; pass < 4; ++pass) {
            int row = pass * 16 + wr;
            ushort4 val;
            val.x = f2bf(ts[k0 + 0][row]);
            val.y = f2bf(ts[k0 + 1][row]);
            val.z = f2bf(ts[k0 + 2][row]);
            val.w = f2bf(ts[k0 + 3][row]);
            *(ushort4*)(&dst[(size_t)(bn + row) * K + bk + k0]) = val;
        }
    } else {
        int row = (bid - 3456) * 4 + (t >> 6);
        int lane = t & 63;
        int s = row & (Sdim - 1);
        long id = ids[row];
        const float4* te = (const float4*)(tok + id * (long)Ddim);
        const float4* pe = (const float4*)(pos + (long)s * Ddim);
        float4 v[3];
        float ls = 0.f, lq = 0.f;
        #pragma unroll
        for (int i = 0; i < 3; ++i) {
            float4 a = te[i * 64 + lane], p = pe[i * 64 + lane];
            v[i].x = a.x + p.x; v[i].y = a.y + p.y; v[i].z = a.z + p.z; v[i].w = a.w + p.w;
            ls += v[i].x + v[i].y + v[i].z + v[i].w;
            lq += v[i].x * v[i].x + v[i].y * v[i].y + v[i].z * v[i].z + v[i].w * v[i].w;
        }
        #pragma unroll
        for (int o = 32; o; o >>= 1) { ls += __shfl_xor(ls, o, 64); lq += __shfl_xor(lq, o, 64); }
        float mu = ls / Ddim;
        float var = lq / Ddim - mu * mu;
        float rs = rsqrtf(var + 1e-5f);
        const float4* g4 = (const float4*)lng;
        const float4* b4 = (const float4*)lnb;
        float4* xr = (float4*)(x + (long)row * Ddim);
        ushort4* xbr = (ushort4*)(xb + (long)row * Ddim);
        #pragma unroll
        for (int i = 0; i < 3; ++i) {
            float4 gg = g4[i * 64 + lane], bb = b4[i * 64 + lane];
            float4 o;
            o.x = (v[i].x - mu) * rs * gg.x + bb.x;
            o.y = (v[i].y - mu) * rs * gg.y + bb.y;
            o.z = (v[i].z - mu) * rs * gg.z + bb.z;
            o.w = (v[i].w - mu) * rs * gg.w + bb.w;
            xr[i * 64 + lane] = o;
            ushort4 ob; ob.x = f2bf(o.x); ob.y = f2bf(o.y); ob.z = f2bf(o.z); ob.w = f2bf(o.w);
            xbr[i * 64 + lane] = ob;
        }
    }
}

// ---------------- residual + 8-slice splitK reduce + col-bias + LN ----------------
__global__ __launch_bounds__(64) void k_ln_res8(float* __restrict__ x,
        const float* __restrict__ pr8, const float* __restrict__ bias,
        const float* __restrict__ g, const float* __restrict__ b,
        ushort* __restrict__ xb) {
    long row = blockIdx.x;
    int t = threadIdx.x;
    const float4* xr = (const float4*)(x + row * Ddim);
    const float4* bi = (const float4*)bias;
    const float4* p[8];
    #pragma unroll
    for (int k = 0; k < 8; ++k)
        p[k] = (const float4*)(pr8 + (size_t)k * MNSZ + row * Ddim);
    float4 v[3];
    float ls = 0.f, lq = 0.f;
    #pragma unroll
    for (int i = 0; i < 3; ++i) {
        int ii = i * 64 + t;
        float4 xa = xr[ii], bb = bi[ii];
        float sx = xa.x + bb.x, sy = xa.y + bb.y, sz = xa.z + bb.z, sw = xa.w + bb.w;
        #pragma unroll
        for (int k = 0; k < 8; ++k) {
            float4 a = p[k][ii];
            sx += a.x; sy += a.y; sz += a.z; sw += a.w;
        }
        v[i].x = sx; v[i].y = sy; v[i].z = sz; v[i].w = sw;
        ls += sx + sy + sz + sw;
        lq += sx * sx + sy * sy + sz * sz + sw * sw;
    }
    #pragma unroll
    for (int o = 32; o; o >>= 1) { ls += __shfl_xor(ls, o, 64); lq += __shfl_xor(lq, o, 64); }
    float mu = ls / Ddim;
    float var = lq / Ddim - mu * mu;
    float rs = rsqrtf(var + 1e-5f);
    const float4* g4 = (const float4*)g;
    const float4* b4 = (const float4*)b;
    float4* xw = (float4*)(x + row * Ddim);
    ushort4* xbr = (ushort4*)(xb + row * Ddim);
    #pragma unroll
    for (int i = 0; i < 3; ++i) {
        float4 gg = g4[i * 64 + t], bb = b4[i * 64 + t];
        float4 o;
        o.x = (v[i].x - mu) * rs * gg.x + bb.x;
        o.y = (v[i].y - mu) * rs * gg.y + bb.y;
        o.z = (v[i].z - mu) * rs * gg.z + bb.z;
        o.w = (v[i].w - mu) * rs * gg.w + bb.w;
        xw[i * 64 + t] = o;
        ushort4 ob; ob.x = f2bf(o.x); ob.y = f2bf(o.y); ob.z = f2bf(o.z); ob.w = f2bf(o.w);
        xbr[i * 64 + t] = ob;
    }
}

// ---------------- QKV GEMM: 128x96 tile ----------------
__global__ __launch_bounds__(256) void k_gemm_qkv(
        const ushort* __restrict__ A, const ushort* __restrict__ Wt,
        const float* __restrict__ bias, ushort* __restrict__ Cout,
        int M, int N, int K)
{
    __shared__ ushort As[2][128 * 32];
    __shared__ ushort Bs[2][96 * 32];
    const int t = threadIdx.x;
    const int nwg = gridDim.x * gridDim.y;
    const int wgid = blockIdx.y * gridDim.x + blockIdx.x;
    const int q8 = nwg >> 3, r8 = nwg & 7;
    const int xcd = wgid & 7, idx = wgid >> 3;
    const int swz = (xcd < r8 ? xcd * (q8 + 1) : r8 * (q8 + 1) + (xcd - r8) * q8) + idx;
    const int bm = (swz / gridDim.x) * 128;
    const int bn = (swz % gridDim.x) * 96;
    const int lane = t & 63;
    const int wv = t >> 6;
    const int wm = (wv >> 1) * 64;
    const int wn = (wv & 1) * 48;

    const int srow = t >> 2;
    const int scol = (t & 3) * 8;
    const ushort* gA0 = A + (size_t)(bm + srow) * K + scol;
    const ushort* gA1 = A + (size_t)(bm + 64 + srow) * K + scol;
    const ushort* gB0 = Wt + (size_t)(bn + srow) * K + scol;
    const ushort* gB1 = Wt + (size_t)(bn + 64 + srow) * K + scol;

    f32x4 acc[4][3] = {};
    const int frow = lane & 15;
    const int koff = (lane >> 4) * 8;

    auto stage = [&](int d, int k0) {
        gload16(gA0 + k0, &As[d][t * 8]);
        gload16(gA1 + k0, &As[d][2048 + t * 8]);
        gload16(gB0 + k0, &Bs[d][t * 8]);
        if (t < 128) gload16(gB1 + k0, &Bs[d][2048 + t * 8]);
    };

    stage(0, 0);
    __syncthreads();
    const int niter = K / 32;
    int cur = 0;
    for (int it = 0; it < niter; ++it) {
        if (it + 1 < niter) stage(cur ^ 1, (it + 1) * 32);
        bf16x8 af[4], bfv[3];
        #pragma unroll
        for (int mi = 0; mi < 4; ++mi)
            af[mi] = *reinterpret_cast<const bf16x8*>(&As[cur][(wm + mi * 16 + frow) * 32 + koff]);
        #pragma unroll
        for (int ni = 0; ni < 3; ++ni)
            bfv[ni] = *reinterpret_cast<const bf16x8*>(&Bs[cur][(wn + ni * 16 + frow) * 32 + koff]);
        #pragma unroll
        for (int mi = 0; mi < 4; ++mi)
            #pragma unroll
            for (int ni = 0; ni < 3; ++ni)
                acc[mi][ni] = __builtin_amdgcn_mfma_f32_16x16x32_bf16(af[mi], bfv[ni], acc[mi][ni], 0, 0, 0);
        __syncthreads();
        cur ^= 1;
    }
    const int crow0 = (lane >> 4) * 4;
    const int ccol = lane & 15;
    #pragma unroll
    for (int mi = 0; mi < 4; ++mi) {
        #pragma unroll
        for (int ni = 0; ni < 3; ++ni) {
            int gc = bn + wn + ni * 16 + ccol;
            float bv = bias[gc];
            #pragma unroll
            for (int j = 0; j < 4; ++j) {
                int gr = bm + wm + mi * 16 + crow0 + j;
                Cout[(size_t)gr * N + gc] = f2bf(acc[mi][ni][j] + bv);
            }
        }
    }
}

// ---------------- bf16 MFMA GEMM 128xBN (dbuf + XCD swizzle), bias+opt GELU ----------------
template<int ACT, int OUTBF16, int BN>
__global__ __launch_bounds__(256) void k_gemm_bf16(
        const ushort* __restrict__ A, const ushort* __restrict__ Wt,
        const float* __restrict__ bias, void* __restrict__ Cout,
        int M, int N, int K)
{
    __shared__ ushort As[2][128 * 32];
    __shared__ ushort Bs[2][BN * 32];
    const int t = threadIdx.x;
    const int nwg = gridDim.x * gridDim.y;
    const int wgid = blockIdx.y * gridDim.x + blockIdx.x;
    const int q8 = nwg >> 3, r8 = nwg & 7;
    const int xcd = wgid & 7, idx = wgid >> 3;
    const int swz = (xcd < r8 ? xcd * (q8 + 1) : r8 * (q8 + 1) + (xcd - r8) * q8) + idx;
    const int bm = (swz / gridDim.x) * 128;
    const int bn = (swz % gridDim.x) * BN;
    const int lane = t & 63;
    const int wv = t >> 6;
    const int wm = (wv >> 1) * 64;
    const int wn = (wv & 1) * (BN / 2);
    constexpr int NF = BN / 32;   // N-fragments per wave

    const int srow = t >> 2;
    const int scol = (t & 3) * 8;
    const ushort* gA0 = A + (size_t)(bm + srow) * K + scol;
    const ushort* gA1 = A + (size_t)(bm + 64 + srow) * K + scol;
    const ushort* gB0 = Wt + (size_t)(bn + srow) * K + scol;
    const ushort* gB1 = Wt + (size_t)(bn + 64 + srow) * K + scol;

    f32x4 acc[4][NF] = {};
    const int frow = lane & 15;
    const int koff = (lane >> 4) * 8;

    auto stage = [&](int d, int k0) {
        gload16(gA0 + k0, &As[d][t * 8]);
        gload16(gA1 + k0, &As[d][2048 + t * 8]);
        gload16(gB0 + k0, &Bs[d][t * 8]);
        if constexpr (BN == 128) gload16(gB1 + k0, &Bs[d][2048 + t * 8]);
    };

    stage(0, 0);
    __syncthreads();
    const int niter = K / 32;
    int cur = 0;
    for (int it = 0; it < niter; ++it) {
        if (it + 1 < niter) stage(cur ^ 1, (it + 1) * 32);
        bf16x8 af[4], bfv[NF];
        #pragma unroll
        for (int mi = 0; mi < 4; ++mi)
            af[mi] = *reinterpret_cast<const bf16x8*>(&As[cur][(wm + mi * 16 + frow) * 32 + koff]);
        #pragma unroll
        for (int ni = 0; ni < NF; ++ni)
            bfv[ni] = *reinterpret_cast<const bf16x8*>(&Bs[cur][(wn + ni * 16 + frow) * 32 + koff]);
        #pragma unroll
        for (int mi = 0; mi < 4; ++mi)
            #pragma unroll
            for (int ni = 0; ni < NF; ++ni)
                acc[mi][ni] = __builtin_amdgcn_mfma_f32_16x16x32_bf16(af[mi], bfv[ni], acc[mi][ni], 0, 0, 0);
        __syncthreads();
        cur ^= 1;
    }
    const int crow0 = (lane >> 4) * 4;
    const int ccol = lane & 15;
    #pragma unroll
    for (int mi = 0; mi < 4; ++mi) {
        #pragma unroll
        for (int ni = 0; ni < NF; ++ni) {
            int gc = bn + wn + ni * 16 + ccol;
            float bv = bias[gc];
            #pragma unroll
            for (int j = 0; j < 4; ++j) {
                int gr = bm + wm + mi * 16 + crow0 + j;
                float v = acc[mi][ni][j] + bv;
                if (ACT == 1) {
                    float y = 0.7978845608f * (v + 0.044715f * v * v * v);
                    float e = __expf(2.f * y);
                    v = v * (1.f - 1.f / (e + 1.f));
                }
                if (OUTBF16) ((ushort*)Cout)[(size_t)gr * N + gc] = f2bf(v);
                else         ((float*)Cout)[(size_t)gr * N + gc] = v;
            }
        }
    }
}

// ---------------- splitK bf16 MFMA GEMM (dbuf): partial f32, no bias ----------------
__global__ __launch_bounds__(256) void k_gemm_splitk(
        const ushort* __restrict__ A, const ushort* __restrict__ Wt,
        float* __restrict__ Cpart, int M, int N, int K, int Kper)
{
    __shared__ ushort As[2][128 * 32];
    __shared__ ushort Bs[2][128 * 32];
    const int t = threadIdx.x;
    const int ks = blockIdx.z;
    const int nwg = gridDim.x * gridDim.y;
    const int wgid = blockIdx.y * gridDim.x + blockIdx.x;
    const int q8 = nwg >> 3, r8 = nwg & 7;
    const int xcd = wgid & 7, idx = wgid >> 3;
    const int swz = (xcd < r8 ? xcd * (q8 + 1) : r8 * (q8 + 1) + (xcd - r8) * q8) + idx;
    const int bm = (swz / gridDim.x) * 128;
    const int bn = (swz % gridDim.x) * 128;
    const int lane = t & 63;
    const int wv = t >> 6;
    const int wm = (wv >> 1) * 64;
    const int wn = (wv & 1) * 64;

    const int srow = t >> 2;
    const int scol = (t & 3) * 8;
    const int kbase = ks * Kper;
    const ushort* gA0 = A + (size_t)(bm + srow) * K + kbase + scol;
    const ushort* gA1 = A + (size_t)(bm + 64 + srow) * K + kbase + scol;
    const ushort* gB0 = Wt + (size_t)(bn + srow) * K + kbase + scol;
    const ushort* gB1 = Wt + (size_t)(bn + 64 + srow) * K + kbase + scol;

    f32x4 acc[4][4] = {};
    const int frow = lane & 15;
    const int koff = (lane >> 4) * 8;

    auto stage = [&](int d, int k0) {
        gload16(gA0 + k0, &As[d][t * 8]);
        gload16(gA1 + k0, &As[d][2048 + t * 8]);
        gload16(gB0 + k0, &Bs[d][t * 8]);
        gload16(gB1 + k0, &Bs[d][2048 + t * 8]);
    };

    stage(0, 0);
    __syncthreads();
    const int niter = Kper / 32;
    int cur = 0;
    for (int it = 0; it < niter; ++it) {
        if (it + 1 < niter) stage(cur ^ 1, (it + 1) * 32);
        bf16x8 af[4], bfv[4];
        #pragma unroll
        for (int mi = 0; mi < 4; ++mi)
            af[mi] = *reinterpret_cast<const bf16x8*>(&As[cur][(wm + mi * 16 + frow) * 32 + koff]);
        #pragma unroll
        for (int ni = 0; ni < 4; ++ni)
            bfv[ni] = *reinterpret_cast<const bf16x8*>(&Bs[cur][(wn + ni * 16 + frow) * 32 + koff]);
        #pragma unroll
        for (int mi = 0; mi < 4; ++mi)
            #pragma unroll
            for (int ni = 0; ni < 4; ++ni)
                acc[mi][ni] = __builtin_amdgcn_mfma_f32_16x16x32_bf16(af[mi], bfv[ni], acc[mi][ni], 0, 0, 0);
        __syncthreads();
        cur ^= 1;
    }
    float* outp = Cpart + (size_t)ks * M * N;
    const int crow0 = (lane >> 4) * 4;
    const int ccol = lane & 15;
    #pragma unroll
    for (int mi = 0; mi < 4; ++mi) {
        #pragma unroll
        for (int ni = 0; ni < 4; ++ni) {
            int gc = bn + wn + ni * 16 + ccol;
            #pragma unroll
            for (int j = 0; j < 4; ++j) {
                int gr = bm + wm + mi * 16 + crow0 + j;
                outp[(size_t)gr * N + gc] = acc[mi][ni][j];
            }
        }
    }
}

// ---------------- FUSED attention: local flash + global split-S partial ----------------
__global__ __launch_bounds__(256) void k_attn_fused(
        const ushort* __restrict__ qkv, const int* __restrict__ isg,
        const int* __restrict__ glob, const int* __restrict__ amask,
        ushort* __restrict__ ao, float* __restrict__ gpart)
{
    __shared__ __align__(16) char smem[38400];
    const int bid = blockIdx.x;
    const int t = threadIdx.x;

    if (bid < NLOC) {
        ushort* Kb   = (ushort*)smem;
        ushort* Vt   = (ushort*)(smem + 8192);
        ushort* Plds = (ushort*)(smem + 17408);
        float* maskLDS = (float*)(smem + 35840);
        int*   rowg    = (int*)(smem + 37632);

        const int n = bid & 15, h = (bid >> 4) % Hdim, b = bid / (16 * Hdim);
        const int lane = t & 63, wv = t >> 6;
        const int R0 = b * Sdim;
        const int l15 = lane & 15, l4 = lane >> 4;

        for (int i = t; i < 448; i += 256) {
            int ok;
            if (i < 384) {
                int pos = n * Cdim + i - Cdim;
                ok = (pos >= 0 && pos < Sdim);
                if (ok) ok = (amask[b * Sdim + pos] != 0) && (isg[pos] == 0);
            } else {
                int g = i - 384;
                int gp = (g < Gdim) ? glob[g] : 0;
                ok = (g < Gdim) && (amask[b * Sdim + gp] != 0);
            }
            maskLDS[i] = ok ? 0.f : -1e9f;
        }
        if (t < 128) rowg[t] = isg[n * Cdim + t];

        bf16x8 qf[2][2];
        #pragma unroll
        for (int qi = 0; qi < 2; ++qi)
            #pragma unroll
            for (int kh = 0; kh < 2; ++kh)
                qf[qi][kh] = *reinterpret_cast<const bf16x8*>(
                    qkv + (size_t)(R0 + n * Cdim + wv * 32 + qi * 16 + l15) * QKVS
                        + h * DHdim + kh * 32 + l4 * 8);

        f32x4 accO[2][4] = {};
        float mrow[2][4], lrow[2][4];
        #pragma unroll
        for (int qi = 0; qi < 2; ++qi)
            #pragma unroll
            for (int j = 0; j < 4; ++j) { mrow[qi][j] = -1e30f; lrow[qi][j] = 0.f; }

        const int jj = t >> 3;
        const int c16 = t & 7;

        auto ldone = [&](int j, ushort8v& kr, ushort8v& vr) {
            int pos = 0; bool ok;
            if (j < 384) { pos = n * Cdim + j - Cdim; ok = (pos >= 0 && pos < Sdim); }
            else { int g = j - 384; ok = (g < Gdim); if (ok) pos = glob[g]; }
            ushort8v z = {};
            if (ok) {
                const ushort* kp = qkv + (size_t)(R0 + pos) * QKVS + Ddim + h * DHdim + c16 * 8;
                kr = *reinterpret_cast<const ushort8v*>(kp);
                vr = *reinterpret_cast<const ushort8v*>(kp + Ddim);
            } else { kr = z; vr = z; }
        };

        ushort8v kr0, kr1, vr0, vr1, nk0 = {}, nk1 = {}, nv0 = {}, nv1 = {};
        ldone(jj, kr0, vr0);
        ldone(jj + 32, kr1, vr1);

        for (int kt = 0; kt < 7; ++kt) {
            __syncthreads();
            *reinterpret_cast<ushort8v*>(&Kb[jj * 64 + ((c16 ^ (jj & 7)) * 8)]) = kr0;
            *reinterpret_cast<ushort8v*>(&Kb[(jj + 32) * 64 + ((c16 ^ (jj & 7)) * 8)]) = kr1;
            #pragma unroll
            for (int e = 0; e < 8; ++e) {
                Vt[(c16 * 8 + e) * 72 + jj] = vr0[e];
                Vt[(c16 * 8 + e) * 72 + 32 + jj] = vr1[e];
            }
            if (kt < 6) {
                int base_j = (kt + 1) * 64 + jj;
                ldone(base_j, nk0, nv0);
                ldone(base_j + 32, nk1, nv1);
            }
            __syncthreads();

            bool active = (kt == 6) || ((kt * 64 + 63 >= wv * 32) && (kt * 64 <= wv * 32 + 287));
            if (active) {
                bf16x8 kf[4][2];
                #pragma unroll
                for (int kj = 0; kj < 4; ++kj) {
                    int key = kj * 16 + l15;
                    #pragma unroll
                    for (int kh = 0; kh < 2; ++kh) {
                        int cc = (kh * 4 + l4) ^ (key & 7);
                        kf[kj][kh] = *reinterpret_cast<const bf16x8*>(&Kb[key * 64 + cc * 8]);
                    }
                }
                float ma[4];
                #pragma unroll
                for (int kj = 0; kj < 4; ++kj) ma[kj] = maskLDS[kt * 64 + kj * 16 + l15];

                #pragma unroll
                for (int qi = 0; qi < 2; ++qi) {
                    f32x4 s[4] = {};
                    #pragma unroll
                    for (int kj = 0; kj < 4; ++kj)
                        #pragma unroll
                        for (int kh = 0; kh < 2; ++kh)
                            s[kj] = __builtin_amdgcn_mfma_f32_16x16x32_bf16(qf[qi][kh], kf[kj][kh], s[kj], 0, 0, 0);

                    float sf[4][4];
                    #pragma unroll
                    for (int kj = 0; kj < 4; ++kj) {
                        int key = kt * 64 + kj * 16 + l15;
                        #pragma unroll
                        for (int j = 0; j < 4; ++j) {
                            int cq = wv * 32 + qi * 16 + l4 * 4 + j;
                            float sv = s[kj][j] * 0.125f + ma[kj];
                            bool band = (key >= 384) || ((unsigned)(key - cq) <= 256u);
                            sf[kj][j] = band ? sv : sv - 1e9f;
                        }
                    }
                    float mnew[4], corr[4];
                    #pragma unroll
                    for (int j = 0; j < 4; ++j) {
                        float v = fmaxf(fmaxf(sf[0][j], sf[1][j]), fmaxf(sf[2][j], sf[3][j]));
                        v = fmaxf(v, __shfl_xor(v, 1, 64));
                        v = fmaxf(v, __shfl_xor(v, 2, 64));
                        v = fmaxf(v, __shfl_xor(v, 4, 64));
                        v = fmaxf(v, __shfl_xor(v, 8, 64));
                        mnew[j] = fmaxf(mrow[qi][j], v);
                        corr[j] = __expf(mrow[qi][j] - mnew[j]);
                        mrow[qi][j] = mnew[j];
                    }
                    float ps[4][4];
                    #pragma unroll
                    for (int kj = 0; kj < 4; ++kj)
                        #pragma unroll
                        for (int j = 0; j < 4; ++j)
                            ps[kj][j] = __expf(sf[kj][j] - mnew[j]);
                    #pragma unroll
                    for (int j = 0; j < 4; ++j) {
                        float r = (ps[0][j] + ps[1][j]) + (ps[2][j] + ps[3][j]);
                        r += __shfl_xor(r, 1, 64);
                        r += __shfl_xor(r, 2, 64);
                        r += __shfl_xor(r, 4, 64);
                        r += __shfl_xor(r, 8, 64);
                        lrow[qi][j] = lrow[qi][j] * corr[j] + r;
                    }
                    bool need = (corr[0] < 1.f) || (corr[1] < 1.f) || (corr[2] < 1.f) || (corr[3] < 1.f);
                    if (__any((int)need)) {
                        #pragma unroll
                        for (int dt = 0; dt < 4; ++dt)
                            #pragma unroll
                            for (int j = 0; j < 4; ++j)
                                accO[qi][dt][j] *= corr[j];
                    }
                    #pragma unroll
                    for (int kj = 0; kj < 4; ++kj)
                        #pragma unroll
                        for (int j = 0; j < 4; ++j)
                            Plds[wv * 2304 + (qi * 16 + l4 * 4 + j) * 72 + kj * 16 + l15] = f2bf(ps[kj][j]);
                }
                #pragma unroll
                for (int qi = 0; qi < 2; ++qi) {
                    #pragma unroll
                    for (int ks = 0; ks < 2; ++ks) {
                        bf16x8 af = *reinterpret_cast<const bf16x8*>(
                            &Plds[wv * 2304 + (qi * 16 + l15) * 72 + ks * 32 + l4 * 8]);
                        #pragma unroll
                        for (int dt = 0; dt < 4; ++dt) {
                            bf16x8 vf = *reinterpret_cast<const bf16x8*>(
                                &Vt[(dt * 16 + l15) * 72 + ks * 32 + l4 * 8]);
                            accO[qi][dt] = __builtin_amdgcn_mfma_f32_16x16x32_bf16(af, vf, accO[qi][dt], 0, 0, 0);
                        }
                    }
                }
            }
            kr0 = nk0; kr1 = nk1; vr0 = nv0; vr1 = nv1;
        }

        #pragma unroll
        for (int qi = 0; qi < 2; ++qi) {
            float inv[4];
            #pragma unroll
            for (int j = 0; j < 4; ++j) inv[j] = 1.f / lrow[qi][j];
            #pragma unroll
            for (int dt = 0; dt < 4; ++dt) {
                #pragma unroll
                for (int j = 0; j < 4; ++j) {
                    int lr = wv * 32 + qi * 16 + l4 * 4 + j;
                    if (!rowg[lr]) {
                        ao[(size_t)(R0 + n * Cdim + lr) * Ddim + h * DHdim + dt * 16 + l15] =
                            f2bf(accO[qi][dt][j] * inv[j]);
                    }
                }
            }
        }
    } else {
        float* qsg = (float*)smem;
        float* sP  = (float*)(smem + 4352);
        float* mg  = (float*)(smem + 21760);
        float* lg  = mg + 17;

        const int e = bid - NLOC;
        const int sc = e & 7, h = (e >> 3) % Hdim, b = e / (8 * Hdim);
        const int R0 = b * Sdim;

        for (int i = t; i < Gdim * DHdim; i += 256) {
            int g = i >> 6, d = i & 63;
            qsg[i] = bf2f(qkv[(size_t)(R0 + glob[g]) * QKVS + h * DHdim + d]) * 0.125f;
        }
        __syncthreads();

        const int r = sc * 256 + t;
        float s[Gdim] = {};
        {
            const ushort8v* kr = (const ushort8v*)(qkv + (size_t)(R0 + r) * QKVS + Ddim + h * DHdim);
            #pragma unroll
            for (int cc = 0; cc < 8; ++cc) {
                ushort8v kv = kr[cc];
                #pragma unroll
                for (int ee = 0; ee < 8; ++ee) {
                    float kf = bf2f(kv[ee]);
                    int d = cc * 8 + ee;
                    #pragma unroll
                    for (int g = 0; g < Gdim; ++g) s[g] += qsg[g * 64 + d] * kf;
                }
            }
        }
        bool okr = (amask[b * Sdim + r] != 0);
        #pragma unroll
        for (int g = 0; g < Gdim; ++g) sP[g * 256 + t] = okr ? s[g] : -1e9f;
        __syncthreads();

        const int wvv = t >> 6, lane = t & 63;
        for (int g = wvv; g < Gdim; g += 4) {
            float a0 = sP[g * 256 + lane];
            float a1 = sP[g * 256 + 64 + lane];
            float a2 = sP[g * 256 + 128 + lane];
            float a3 = sP[g * 256 + 192 + lane];
            float mx = fmaxf(fmaxf(a0, a1), fmaxf(a2, a3));
            #pragma unroll
            for (int o = 32; o; o >>= 1) mx = fmaxf(mx, __shfl_xor(mx, o, 64));
            float e0 = __expf(a0 - mx), e1 = __expf(a1 - mx);
            float e2 = __expf(a2 - mx), e3 = __expf(a3 - mx);
            float es = (e0 + e1) + (e2 + e3);
            #pragma unroll
            for (int o = 32; o; o >>= 1) es += __shfl_xor(es, o, 64);
            sP[g * 256 + lane] = e0;
            sP[g * 256 + 64 + lane] = e1;
            sP[g * 256 + 128 + lane] = e2;
            sP[g * 256 + 192 + lane] = e3;
            if (lane == 0) { mg[g] = mx; lg[g] = es; }
        }
        __syncthreads();

        float* pr = gpart + (((size_t)b * Hdim + h) * 8 + sc) * (Gdim * 66);
        for (int o = t; o < Gdim * DHdim; o += 256) {
            int g = o >> 6, d = o & 63;
            const ushort* vp = qkv + (size_t)(R0 + sc * 256) * QKVS + 2 * Ddim + h * DHdim + d;
            float acc = 0.f;
            for (int k = 0; k < 256; ++k)
                acc += sP[g * 256 + k] * bf2f(vp[(size_t)k * QKVS]);
            pr[g * 66 + 2 + d] = acc;
        }
        if (t < Gdim) { pr[t * 66 + 0] = mg[t]; pr[t * 66 + 1] = lg[t]; }
    }
}

// ---------------- global-attn chunk reduce ----------------
__global__ __launch_bounds__(64) void k_globred(const float* __restrict__ gpart,
        const int* __restrict__ glob, ushort* __restrict__ ao) {
    int g = blockIdx.x, h = blockIdx.y, b = blockIdx.z;
    int lane = threadIdx.x;
    float M = -1e30f, L = 0.f, A = 0.f;
    for (int sc = 0; sc < 8; ++sc) {
        const float* pp = gpart + (((size_t)b * Hdim + h) * 8 + sc) * (Gdim * 66) + g * 66;
        float m = pp[0], l = pp[1], a = pp[2 + lane];
        float nM = fmaxf(M, m);
        float c1 = __expf(M - nM), c2 = __expf(m - nM);
        L = L * c1 + l * c2;
        A = A * c1 + a * c2;
        M = nM;
    }
    ao[(size_t)(b * Sdim + glob[g]) * Ddim + h * DHdim + lane] = f2bf(A / L);
}

// ---------------- classification head ----------------
__global__ __launch_bounds__(256) void k_head(const float* __restrict__ x,
        const int* __restrict__ glob, const float* __restrict__ Wh,
        const float* __restrict__ bh, const float* __restrict__ Wout,
        const float* __restrict__ bout, float* __restrict__ out) {
    int i = blockIdx.x;
    int b = i / 14, j = i % 14;
    __shared__ float emb[2 * Ddim];
    __shared__ float hp[2][128];
    __shared__ float hid[HIDd];
    int t = threadIdx.x;
    int p = glob[j + 2];
    for (int d = t; d < Ddim; d += 256) {
        emb[d] = x[(long)b * Sdim * Ddim + d];
        emb[Ddim + d] = x[((long)b * Sdim + p) * Ddim + d];
    }
    __syncthreads();
    int nn = t & 127, half = t >> 7;
    float s = 0.f;
    if (nn < HIDd) {
        int k0 = half * Ddim;
        for (int k1 = 0; k1 < Ddim; ++k1) s += emb[k0 + k1] * Wh[(k0 + k1) * HIDd + nn];
    }
    hp[half][nn] = s;
    __syncthreads();
    if (t < HIDd) hid[t] = fmaxf(hp[0][t] + hp[1][t] + bh[t], 0.f);
    __syncthreads();
    if (t < NCLSd) {
        float s2 = bout[t];
        for (int o = 0; o < HIDd; ++o) s2 += hid[o] * Wout[o * NCLSd + t];
        out[i * NCLSd + t] = s2;
    }
}

extern "C" void kernel_launch(void* const* d_in, const int* in_sizes, int n_in,
                              void* d_out, int out_size, void* d_ws, size_t ws_size,
                              hipStream_t stream) {
    const int*   ids   = (const int*)d_in[0];
    const int*   am    = (const int*)d_in[1];
    const float* tok   = (const float*)d_in[2];
    const float* pos   = (const float*)d_in[3];
    const float* lneg  = (const float*)d_in[4];
    const float* lneb  = (const float*)d_in[5];
    const float* Wq    = (const float*)d_in[6];
    const float* bq    = (const float*)d_in[7];
    const float* Wk    = (const float*)d_in[8];
    const float* bk    = (const float*)d_in[9];
    const float* Wv    = (const float*)d_in[10];
    const float* bv    = (const float*)d_in[11];
    const float* Wo    = (const float*)d_in[12];
    const float* bo    = (const float*)d_in[13];
    const float* ln1g  = (const float*)d_in[14];
    const float* ln1b  = (const float*)d_in[15];
    const float* W1    = (const float*)d_in[16];
    const float* b1    = (const float*)d_in[17];
    const float* W2    = (const float*)d_in[18];
    const float* b2    = (const float*)d_in[19];
    const float* ln2g  = (const float*)d_in[20];
    const float* ln2b  = (const float*)d_in[21];
    const float* Wh    = (const float*)d_in[22];
    const float* bh    = (const float*)d_in[23];
    const float* Wout  = (const float*)d_in[24];
    const float* bout  = (const float*)d_in[25];
    float* out = (float*)d_out;

    char* ws = (char*)d_ws;
    const size_t SZ = (size_t)MROWS * Ddim * sizeof(float);
    const size_t HB = SZ / 2;
    size_t off = 0;
    float*  x    = (float*)(ws + off);  off += SZ;
    float*  pr8  = (float*)(ws + off);  off += 8 * SZ;   // splitK partials (8 slices)
    ushort* xb   = (ushort*)(ws + off); off += HB;
    ushort* qkvB = (ushort*)(ws + off); off += (size_t)MROWS * QKVS * 2;
    ushort* aoB  = (ushort*)(ws + off); off += HB;
    ushort* hh   = (ushort*)(ws + off); off += (size_t)MROWS * FFdim * 2;
    const size_t WSMALL = (size_t)Ddim * Ddim;
    const size_t WBIG   = (size_t)Ddim * FFdim;
    const size_t WL     = 4 * WSMALL + 2 * WBIG;
    ushort* wts = (ushort*)(ws + off); off += WL * Ldim * 2;
    float* bqkv = (float*)(ws + off);  off += Ldim * QKVS * sizeof(float);
    float* gpart = (float*)(ws + off); off += (size_t)Bdim * Hdim * 8 * Gdim * 66 * sizeof(float);
    int* glob = (int*)(ws + off); off += 256;
    int* isg  = (int*)(ws + off);

    k_findsep<<<1, 1024, 0, stream>>>(ids, glob, isg, bq, bk, bv, bqkv);
    k_prolog<<<3456 + MROWS / 4, 256, 0, stream>>>(Wq, Wk, Wv, Wo, W1, W2, wts,
                                                   ids, tok, pos, lneg, lneb, x, xb);

    dim3 gQKV(QKVS / 96, MROWS / 128);              // 768 blocks
    dim3 gFF(FFdim / 64, MROWS / 128);              // 48 x 32 = 1536 blocks (BN=64)
    dim3 gSK(Ddim / 128, MROWS / 128, 8);           // 1536 blocks, ~6/CU
    dim3 gred(Gdim, Hdim, Bdim);

    for (int l = 0; l < Ldim; ++l) {
        ushort* base = wts + l * WL;
        ushort* Wqkvt = base;
        ushort* Wot = base + 3 * WSMALL;
        ushort* W1t = base + 4 * WSMALL;
        ushort* W2t = base + 4 * WSMALL + WBIG;
        k_gemm_qkv<<<gQKV, 256, 0, stream>>>(xb, Wqkvt, bqkv + l * QKVS, qkvB, MROWS, QKVS, Ddim);
        k_attn_fused<<<NLOC + NGP, 256, 0, stream>>>(qkvB, isg, glob, am, aoB, gpart);
        k_globred<<<gred, 64, 0, stream>>>(gpart, glob, aoB);
        k_gemm_splitk<<<gSK, 256, 0, stream>>>(aoB, Wot, pr8, MROWS, Ddim, Ddim, Ddim / 8);
        k_ln_res8<<<MROWS, 64, 0, stream>>>(x, pr8, bo + l * Ddim, ln1g + l * Ddim, ln1b + l * Ddim, xb);
        k_gemm_bf16<1,1,64><<<gFF, 256, 0, stream>>>(xb, W1t, b1 + l * FFdim, hh, MROWS, FFdim, Ddim);
        k_gemm_splitk<<<gSK, 256, 0, stream>>>(hh, W2t, pr8, MROWS, Ddim, FFdim, FFdim / 8);
        k_ln_res8<<<MROWS, 64, 0, stream>>>(x, pr8, b2 + l * Ddim, ln2g + l * Ddim, ln2b + l * Ddim, xb);
    }
    k_head<<<Bdim * (NSEPd - 2), 256, 0, stream>>>(x, glob, Wh, bh, Wout, bout, out);
}

// Round 12
// 473.083 us; speedup vs baseline: 1.1757x; 1.1757x over previous
//
#include <hip/hip_runtime.h>
#include <hip/hip_bf16.h>
#include <math.h>

#define Sdim 2048
#define Bdim 2
#define Ddim 768
#define Hdim 12
#define DHdim 64
#define Ldim 2
#define Cdim 128
#define NCdim 16
#define FFdim 3072
#define Gdim 17
#define NSEPd 16
#define HIDd 100
#define NCLSd 7
#define SEPID 2
#define MROWS (Bdim*Sdim)
#define QKVS 2304
#define MNSZ (MROWS*Ddim)

typedef __bf16 bf16_t;
typedef bf16_t bf16x8 __attribute__((ext_vector_type(8)));
typedef float f32x4 __attribute__((ext_vector_type(4)));
typedef ushort ushort8v __attribute__((ext_vector_type(8)));

__device__ __forceinline__ ushort f2bf(float f) {
    union { float f; unsigned u; } a; a.f = f;
    unsigned u = a.u;
    unsigned r = (u + 0x7fffu + ((u >> 16) & 1u)) >> 16;
    return (ushort)r;
}
__device__ __forceinline__ float bf2f(ushort h) {
    union { unsigned u; float f; } a; a.u = ((unsigned)h) << 16;
    return a.f;
}
__device__ __forceinline__ void gload16(const ushort* g, ushort* l) {
    __builtin_amdgcn_global_load_lds(
        (const __attribute__((address_space(1))) void*)g,
        (__attribute__((address_space(3))) void*)l, 16, 0, 0);
}

// ---------------- sep finding (ballot + prefix popcount) + bias concat ----------------
__global__ __launch_bounds__(1024) void k_findsep(const int* __restrict__ ids,
        int* __restrict__ glob, int* __restrict__ isg,
        const float* __restrict__ bq, const float* __restrict__ bk,
        const float* __restrict__ bv, float* __restrict__ bqkv) {
    __shared__ unsigned long long mw[32];
    __shared__ int pfx[32];
    int t = threadIdx.x;
    int flg[2];
    #pragma unroll
    for (int pass = 0; pass < 2; ++pass) {
        int p = pass * 1024 + t;
        int f = (ids[p] == SEPID);
        flg[pass] = f;
        unsigned long long m = __ballot(f);
        if ((t & 63) == 0) mw[pass * 16 + (t >> 6)] = m;
    }
    __syncthreads();
    if (t == 0) {
        int c = 0;
        #pragma unroll
        for (int i = 0; i < 32; ++i) { pfx[i] = c; c += __popcll(mw[i]); }
        glob[0] = 0;
    }
    __syncthreads();
    #pragma unroll
    for (int pass = 0; pass < 2; ++pass) {
        int p = pass * 1024 + t;
        int w = pass * 16 + (t >> 6);
        int lane = t & 63;
        int rank = pfx[w] + __popcll(mw[w] & ((1ull << lane) - 1ull));
        int ig = 0;
        if (flg[pass] && rank < NSEPd) { glob[rank + 1] = p; ig = 1; }
        if (p == 0) ig = 1;
        isg[p] = ig;
    }
    for (int idx = t; idx < Ldim * QKVS; idx += 1024) {
        int l = idx / QKVS, i = idx % QKVS;
        float v = (i < Ddim) ? bq[l * Ddim + i]
                : (i < 2 * Ddim) ? bk[l * Ddim + i - Ddim]
                : bv[l * Ddim + i - 2 * Ddim];
        bqkv[idx] = v;
    }
}

// ---------------- ALL weight transposes in ONE kernel ----------------
__global__ __launch_bounds__(256) void k_w2bt_all(
        const float* __restrict__ Wq, const float* __restrict__ Wk,
        const float* __restrict__ Wv, const float* __restrict__ Wo,
        const float* __restrict__ W1, const float* __restrict__ W2,
        ushort* __restrict__ wts) {
    const size_t WSMALL = (size_t)Ddim * Ddim;
    const size_t WBIG   = (size_t)Ddim * FFdim;
    const size_t WL     = 4 * WSMALL + 2 * WBIG;
    int bid = blockIdx.x;
    int l = bid / 1728, r = bid % 1728;
    const float* src; ushort* dst; int K, N, tile;
    ushort* base = wts + (size_t)l * WL;
    if (r < 576) {
        int w = r / 144; tile = r % 144; K = Ddim; N = Ddim;
        src = (w == 0 ? Wq : w == 1 ? Wk : w == 2 ? Wv : Wo) + (size_t)l * WSMALL;
        dst = base + (size_t)w * WSMALL;
    } else if (r < 1152) {
        tile = r - 576; K = Ddim; N = FFdim;
        src = W1 + (size_t)l * WBIG; dst = base + 4 * WSMALL;
    } else {
        tile = r - 1152; K = FFdim; N = Ddim;
        src = W2 + (size_t)l * WBIG; dst = base + 4 * WSMALL + WBIG;
    }
    int ntn = N / 64;
    int bn = (tile % ntn) * 64, bk = (tile / ntn) * 64;

    __shared__ float ts[64][65];
    int t = threadIdx.x;
    int rx = t & 63, ry = t >> 6;
    #pragma unroll
    for (int i = 0; i < 16; ++i) {
        int row = ry * 16 + i;
        ts[row][rx] = src[(size_t)(bk + row) * N + bn + rx];
    }
    __syncthreads();
    int wr = t >> 4;
    int k0 = (t & 15) * 4;
    #pragma unroll
    for (int pass = 0; pass < 4; ++pass) {
        int row = pass * 16 + wr;
        ushort4 val;
        val.x = f2bf(ts[k0 + 0][row]);
        val.y = f2bf(ts[k0 + 1][row]);
        val.z = f2bf(ts[k0 + 2][row]);
        val.w = f2bf(ts[k0 + 3][row]);
        *(ushort4*)(&dst[(size_t)(bn + row) * K + bk + k0]) = val;
    }
}

// ---------------- embedding + LN (1 wave/row, float4) ----------------
__global__ __launch_bounds__(64) void k_embed(const int* __restrict__ ids,
        const float* __restrict__ tok, const float* __restrict__ pos,
        const float* __restrict__ g, const float* __restrict__ b,
        float* __restrict__ x, ushort* __restrict__ xb) {
    int row = blockIdx.x;
    int s = row & (Sdim - 1);
    long id = ids[row];
    const float4* te = (const float4*)(tok + id * (long)Ddim);
    const float4* pe = (const float4*)(pos + (long)s * Ddim);
    int t = threadIdx.x;
    float4 v[3];
    float ls = 0.f, lq = 0.f;
    #pragma unroll
    for (int i = 0; i < 3; ++i) {
        float4 a = te[i * 64 + t], p = pe[i * 64 + t];
        v[i].x = a.x + p.x; v[i].y = a.y + p.y; v[i].z = a.z + p.z; v[i].w = a.w + p.w;
        ls += v[i].x + v[i].y + v[i].z + v[i].w;
        lq += v[i].x * v[i].x + v[i].y * v[i].y + v[i].z * v[i].z + v[i].w * v[i].w;
    }
    #pragma unroll
    for (int o = 32; o; o >>= 1) { ls += __shfl_xor(ls, o, 64); lq += __shfl_xor(lq, o, 64); }
    float mu = ls / Ddim;
    float var = lq / Ddim - mu * mu;
    float rs = rsqrtf(var + 1e-5f);
    const float4* g4 = (const float4*)g;
    const float4* b4 = (const float4*)b;
    float4* xr = (float4*)(x + (long)row * Ddim);
    ushort4* xbr = (ushort4*)(xb + (long)row * Ddim);
    #pragma unroll
    for (int i = 0; i < 3; ++i) {
        float4 gg = g4[i * 64 + t], bb = b4[i * 64 + t];
        float4 o;
        o.x = (v[i].x - mu) * rs * gg.x + bb.x;
        o.y = (v[i].y - mu) * rs * gg.y + bb.y;
        o.z = (v[i].z - mu) * rs * gg.z + bb.z;
        o.w = (v[i].w - mu) * rs * gg.w + bb.w;
        xr[i * 64 + t] = o;
        ushort4 ob; ob.x = f2bf(o.x); ob.y = f2bf(o.y); ob.z = f2bf(o.z); ob.w = f2bf(o.w);
        xbr[i * 64 + t] = ob;
    }
}

// ---------------- residual + 4-slice splitK reduce + col-bias + LN ----------------
__global__ __launch_bounds__(64) void k_ln_res4(float* __restrict__ x,
        const float* __restrict__ pr4, const float* __restrict__ bias,
        const float* __restrict__ g, const float* __restrict__ b,
        ushort* __restrict__ xb) {
    long row = blockIdx.x;
    int t = threadIdx.x;
    const float4* xr = (const float4*)(x + row * Ddim);
    const float4* p0 = (const float4*)(pr4 + row * Ddim);
    const float4* p1 = (const float4*)(pr4 + (size_t)MNSZ + row * Ddim);
    const float4* p2 = (const float4*)(pr4 + 2 * (size_t)MNSZ + row * Ddim);
    const float4* p3 = (const float4*)(pr4 + 3 * (size_t)MNSZ + row * Ddim);
    const float4* bi = (const float4*)bias;
    float4 v[3];
    float ls = 0.f, lq = 0.f;
    #pragma unroll
    for (int i = 0; i < 3; ++i) {
        int ii = i * 64 + t;
        float4 xa = xr[ii], a0 = p0[ii], a1 = p1[ii], a2 = p2[ii], a3 = p3[ii], bb = bi[ii];
        v[i].x = xa.x + ((a0.x + a1.x) + (a2.x + a3.x)) + bb.x;
        v[i].y = xa.y + ((a0.y + a1.y) + (a2.y + a3.y)) + bb.y;
        v[i].z = xa.z + ((a0.z + a1.z) + (a2.z + a3.z)) + bb.z;
        v[i].w = xa.w + ((a0.w + a1.w) + (a2.w + a3.w)) + bb.w;
        ls += v[i].x + v[i].y + v[i].z + v[i].w;
        lq += v[i].x * v[i].x + v[i].y * v[i].y + v[i].z * v[i].z + v[i].w * v[i].w;
    }
    #pragma unroll
    for (int o = 32; o; o >>= 1) { ls += __shfl_xor(ls, o, 64); lq += __shfl_xor(lq, o, 64); }
    float mu = ls / Ddim;
    float var = lq / Ddim - mu * mu;
    float rs = rsqrtf(var + 1e-5f);
    const float4* g4 = (const float4*)g;
    const float4* b4 = (const float4*)b;
    float4* xw = (float4*)(x + row * Ddim);
    ushort4* xbr = (ushort4*)(xb + row * Ddim);
    #pragma unroll
    for (int i = 0; i < 3; ++i) {
        float4 gg = g4[i * 64 + t], bb = b4[i * 64 + t];
        float4 o;
        o.x = (v[i].x - mu) * rs * gg.x + bb.x;
        o.y = (v[i].y - mu) * rs * gg.y + bb.y;
        o.z = (v[i].z - mu) * rs * gg.z + bb.z;
        o.w = (v[i].w - mu) * rs * gg.w + bb.w;
        xw[i * 64 + t] = o;
        ushort4 ob; ob.x = f2bf(o.x); ob.y = f2bf(o.y); ob.z = f2bf(o.z); ob.w = f2bf(o.w);
        xbr[i * 64 + t] = ob;
    }
}

// ---------------- bf16 MFMA GEMM (m97 + double-buffered K-loop + XCD swizzle) ----------------
template<int ACT, int OUTBF16>
__global__ __launch_bounds__(256) void k_gemm_bf16(
        const ushort* __restrict__ A, const ushort* __restrict__ Wt,
        const float* __restrict__ bias, void* __restrict__ Cout,
        int M, int N, int K)
{
    __shared__ ushort As[2][128 * 32];
    __shared__ ushort Bs[2][128 * 32];
    const int t = threadIdx.x;
    const int nwg = gridDim.x * gridDim.y;
    const int wgid = blockIdx.y * gridDim.x + blockIdx.x;
    const int q8 = nwg >> 3, r8 = nwg & 7;
    const int xcd = wgid & 7, idx = wgid >> 3;
    const int swz = (xcd < r8 ? xcd * (q8 + 1) : r8 * (q8 + 1) + (xcd - r8) * q8) + idx;
    const int bm = (swz / gridDim.x) * 128;
    const int bn = (swz % gridDim.x) * 128;
    const int lane = t & 63;
    const int wv = t >> 6;
    const int wm = (wv >> 1) * 64;
    const int wn = (wv & 1) * 64;

    const int srow = t >> 2;
    const int scol = (t & 3) * 8;
    const ushort* gA0 = A + (size_t)(bm + srow) * K + scol;
    const ushort* gA1 = A + (size_t)(bm + 64 + srow) * K + scol;
    const ushort* gB0 = Wt + (size_t)(bn + srow) * K + scol;
    const ushort* gB1 = Wt + (size_t)(bn + 64 + srow) * K + scol;

    f32x4 acc[4][4] = {};
    const int frow = lane & 15;
    const int koff = (lane >> 4) * 8;

    auto stage = [&](int d, int k0) {
        gload16(gA0 + k0, &As[d][t * 8]);
        gload16(gA1 + k0, &As[d][2048 + t * 8]);
        gload16(gB0 + k0, &Bs[d][t * 8]);
        gload16(gB1 + k0, &Bs[d][2048 + t * 8]);
    };

    stage(0, 0);
    __syncthreads();
    const int niter = K / 32;
    int cur = 0;
    for (int it = 0; it < niter; ++it) {
        if (it + 1 < niter) stage(cur ^ 1, (it + 1) * 32);
        bf16x8 af[4], bfv[4];
        #pragma unroll
        for (int mi = 0; mi < 4; ++mi)
            af[mi] = *reinterpret_cast<const bf16x8*>(&As[cur][(wm + mi * 16 + frow) * 32 + koff]);
        #pragma unroll
        for (int ni = 0; ni < 4; ++ni)
            bfv[ni] = *reinterpret_cast<const bf16x8*>(&Bs[cur][(wn + ni * 16 + frow) * 32 + koff]);
        #pragma unroll
        for (int mi = 0; mi < 4; ++mi)
            #pragma unroll
            for (int ni = 0; ni < 4; ++ni)
                acc[mi][ni] = __builtin_amdgcn_mfma_f32_16x16x32_bf16(af[mi], bfv[ni], acc[mi][ni], 0, 0, 0);
        __syncthreads();
        cur ^= 1;
    }
    const int crow0 = (lane >> 4) * 4;
    const int ccol = lane & 15;
    #pragma unroll
    for (int mi = 0; mi < 4; ++mi) {
        #pragma unroll
        for (int ni = 0; ni < 4; ++ni) {
            int gc = bn + wn + ni * 16 + ccol;
            float bv = bias[gc];
            #pragma unroll
            for (int j = 0; j < 4; ++j) {
                int gr = bm + wm + mi * 16 + crow0 + j;
                float v = acc[mi][ni][j] + bv;
                if (ACT == 1) {
                    float y = 0.7978845608f * (v + 0.044715f * v * v * v);
                    float e = __expf(2.f * y);
                    v = v * (1.f - 1.f / (e + 1.f));
                }
                if (OUTBF16) ((ushort*)Cout)[(size_t)gr * N + gc] = f2bf(v);
                else         ((float*)Cout)[(size_t)gr * N + gc] = v;
            }
        }
    }
}

// ---------------- splitK bf16 MFMA GEMM (double-buffered): partial f32, no bias ----------------
__global__ __launch_bounds__(256) void k_gemm_splitk(
        const ushort* __restrict__ A, const ushort* __restrict__ Wt,
        float* __restrict__ Cpart, int M, int N, int K, int Kper)
{
    __shared__ ushort As[2][128 * 32];
    __shared__ ushort Bs[2][128 * 32];
    const int t = threadIdx.x;
    const int ks = blockIdx.z;
    const int nwg = gridDim.x * gridDim.y;
    const int wgid = blockIdx.y * gridDim.x + blockIdx.x;
    const int q8 = nwg >> 3, r8 = nwg & 7;
    const int xcd = wgid & 7, idx = wgid >> 3;
    const int swz = (xcd < r8 ? xcd * (q8 + 1) : r8 * (q8 + 1) + (xcd - r8) * q8) + idx;
    const int bm = (swz / gridDim.x) * 128;
    const int bn = (swz % gridDim.x) * 128;
    const int lane = t & 63;
    const int wv = t >> 6;
    const int wm = (wv >> 1) * 64;
    const int wn = (wv & 1) * 64;

    const int srow = t >> 2;
    const int scol = (t & 3) * 8;
    const int kbase = ks * Kper;
    const ushort* gA0 = A + (size_t)(bm + srow) * K + kbase + scol;
    const ushort* gA1 = A + (size_t)(bm + 64 + srow) * K + kbase + scol;
    const ushort* gB0 = Wt + (size_t)(bn + srow) * K + kbase + scol;
    const ushort* gB1 = Wt + (size_t)(bn + 64 + srow) * K + kbase + scol;

    f32x4 acc[4][4] = {};
    const int frow = lane & 15;
    const int koff = (lane >> 4) * 8;

    auto stage = [&](int d, int k0) {
        gload16(gA0 + k0, &As[d][t * 8]);
        gload16(gA1 + k0, &As[d][2048 + t * 8]);
        gload16(gB0 + k0, &Bs[d][t * 8]);
        gload16(gB1 + k0, &Bs[d][2048 + t * 8]);
    };

    stage(0, 0);
    __syncthreads();
    const int niter = Kper / 32;
    int cur = 0;
    for (int it = 0; it < niter; ++it) {
        if (it + 1 < niter) stage(cur ^ 1, (it + 1) * 32);
        bf16x8 af[4], bfv[4];
        #pragma unroll
        for (int mi = 0; mi < 4; ++mi)
            af[mi] = *reinterpret_cast<const bf16x8*>(&As[cur][(wm + mi * 16 + frow) * 32 + koff]);
        #pragma unroll
        for (int ni = 0; ni < 4; ++ni)
            bfv[ni] = *reinterpret_cast<const bf16x8*>(&Bs[cur][(wn + ni * 16 + frow) * 32 + koff]);
        #pragma unroll
        for (int mi = 0; mi < 4; ++mi)
            #pragma unroll
            for (int ni = 0; ni < 4; ++ni)
                acc[mi][ni] = __builtin_amdgcn_mfma_f32_16x16x32_bf16(af[mi], bfv[ni], acc[mi][ni], 0, 0, 0);
        __syncthreads();
        cur ^= 1;
    }
    float* outp = Cpart + (size_t)ks * M * N;
    const int crow0 = (lane >> 4) * 4;
    const int ccol = lane & 15;
    #pragma unroll
    for (int mi = 0; mi < 4; ++mi) {
        #pragma unroll
        for (int ni = 0; ni < 4; ++ni) {
            int gc = bn + wn + ni * 16 + ccol;
            #pragma unroll
            for (int j = 0; j < 4; ++j) {
                int gr = bm + wm + mi * 16 + crow0 + j;
                outp[(size_t)gr * N + gc] = acc[mi][ni][j];
            }
        }
    }
}

// ---------------- MFMA flash local attention, 64-key tiles ----------------
__global__ __launch_bounds__(256) void k_attn_mfma(
        const ushort* __restrict__ qkv, const int* __restrict__ isg,
        const int* __restrict__ glob, const int* __restrict__ amask,
        ushort* __restrict__ ao)
{
    const int n = blockIdx.x, h = blockIdx.y, b = blockIdx.z;
    const int t = threadIdx.x;
    const int lane = t & 63, wv = t >> 6;
    const int R0 = b * Sdim;
    const int l15 = lane & 15, l4 = lane >> 4;

    __shared__ ushort Kb[64 * 64];
    __shared__ ushort Vt[64 * 72];
    __shared__ ushort Plds[4][32 * 72];
    __shared__ float  maskLDS[448];

    for (int i = t; i < 448; i += 256) {
        int ok;
        if (i < 384) {
            int pos = n * Cdim + i - Cdim;
            ok = (pos >= 0 && pos < Sdim);
            if (ok) ok = (amask[b * Sdim + pos] != 0) && (isg[pos] == 0);
        } else {
            int g = i - 384;
            int gp = (g < Gdim) ? glob[g] : 0;
            ok = (g < Gdim) && (amask[b * Sdim + gp] != 0);
        }
        maskLDS[i] = ok ? 0.f : -1e9f;
    }

    bf16x8 qf[2][2];
    #pragma unroll
    for (int qi = 0; qi < 2; ++qi)
        #pragma unroll
        for (int kh = 0; kh < 2; ++kh)
            qf[qi][kh] = *reinterpret_cast<const bf16x8*>(
                qkv + (size_t)(R0 + n * Cdim + wv * 32 + qi * 16 + l15) * QKVS
                    + h * DHdim + kh * 32 + l4 * 8);

    f32x4 accO[2][4] = {};
    float mrow[2][4], lrow[2][4];
    #pragma unroll
    for (int qi = 0; qi < 2; ++qi)
        #pragma unroll
        for (int j = 0; j < 4; ++j) { mrow[qi][j] = -1e30f; lrow[qi][j] = 0.f; }

    const int jj = t >> 3;
    const int c16 = t & 7;

    auto ldone = [&](int j, ushort8v& kr, ushort8v& vr) {
        int pos = 0; bool ok;
        if (j < 384) { pos = n * Cdim + j - Cdim; ok = (pos >= 0 && pos < Sdim); }
        else { int g = j - 384; ok = (g < Gdim); if (ok) pos = glob[g]; }
        ushort8v z = {};
        if (ok) {
            const ushort* kp = qkv + (size_t)(R0 + pos) * QKVS + Ddim + h * DHdim + c16 * 8;
            kr = *reinterpret_cast<const ushort8v*>(kp);
            vr = *reinterpret_cast<const ushort8v*>(kp + Ddim);
        } else { kr = z; vr = z; }
    };

    ushort8v kr0, kr1, vr0, vr1, nk0 = {}, nk1 = {}, nv0 = {}, nv1 = {};
    ldone(jj, kr0, vr0);
    ldone(jj + 32, kr1, vr1);

    for (int kt = 0; kt < 7; ++kt) {
        __syncthreads();
        *reinterpret_cast<ushort8v*>(&Kb[jj * 64 + ((c16 ^ (jj & 7)) * 8)]) = kr0;
        *reinterpret_cast<ushort8v*>(&Kb[(jj + 32) * 64 + ((c16 ^ (jj & 7)) * 8)]) = kr1;
        #pragma unroll
        for (int e = 0; e < 8; ++e) {
            Vt[(c16 * 8 + e) * 72 + jj] = vr0[e];
            Vt[(c16 * 8 + e) * 72 + 32 + jj] = vr1[e];
        }
        if (kt < 6) {
            int base_j = (kt + 1) * 64 + jj;
            ldone(base_j, nk0, nv0);
            ldone(base_j + 32, nk1, nv1);
        }
        __syncthreads();

        bool active = (kt == 6) || ((kt * 64 + 63 >= wv * 32) && (kt * 64 <= wv * 32 + 287));
        if (active) {
            bf16x8 kf[4][2];
            #pragma unroll
            for (int kj = 0; kj < 4; ++kj) {
                int key = kj * 16 + l15;
                #pragma unroll
                for (int kh = 0; kh < 2; ++kh) {
                    int cc = (kh * 4 + l4) ^ (key & 7);
                    kf[kj][kh] = *reinterpret_cast<const bf16x8*>(&Kb[key * 64 + cc * 8]);
                }
            }
            float ma[4];
            #pragma unroll
            for (int kj = 0; kj < 4; ++kj) ma[kj] = maskLDS[kt * 64 + kj * 16 + l15];

            #pragma unroll
            for (int qi = 0; qi < 2; ++qi) {
                f32x4 s[4] = {};
                #pragma unroll
                for (int kj = 0; kj < 4; ++kj)
                    #pragma unroll
                    for (int kh = 0; kh < 2; ++kh)
                        s[kj] = __builtin_amdgcn_mfma_f32_16x16x32_bf16(qf[qi][kh], kf[kj][kh], s[kj], 0, 0, 0);

                float sf[4][4];
                #pragma unroll
                for (int kj = 0; kj < 4; ++kj) {
                    int key = kt * 64 + kj * 16 + l15;
                    #pragma unroll
                    for (int j = 0; j < 4; ++j) {
                        int cq = wv * 32 + qi * 16 + l4 * 4 + j;
                        float sv = s[kj][j] * 0.125f + ma[kj];
                        bool band = (key >= 384) || ((unsigned)(key - cq) <= 256u);
                        sf[kj][j] = band ? sv : sv - 1e9f;
                    }
                }
                float mnew[4], corr[4];
                #pragma unroll
                for (int j = 0; j < 4; ++j) {
                    float v = fmaxf(fmaxf(sf[0][j], sf[1][j]), fmaxf(sf[2][j], sf[3][j]));
                    v = fmaxf(v, __shfl_xor(v, 1, 64));
                    v = fmaxf(v, __shfl_xor(v, 2, 64));
                    v = fmaxf(v, __shfl_xor(v, 4, 64));
                    v = fmaxf(v, __shfl_xor(v, 8, 64));
                    mnew[j] = fmaxf(mrow[qi][j], v);
                    corr[j] = __expf(mrow[qi][j] - mnew[j]);
                    mrow[qi][j] = mnew[j];
                }
                float ps[4][4];
                #pragma unroll
                for (int kj = 0; kj < 4; ++kj)
                    #pragma unroll
                    for (int j = 0; j < 4; ++j)
                        ps[kj][j] = __expf(sf[kj][j] - mnew[j]);
                #pragma unroll
                for (int j = 0; j < 4; ++j) {
                    float r = (ps[0][j] + ps[1][j]) + (ps[2][j] + ps[3][j]);
                    r += __shfl_xor(r, 1, 64);
                    r += __shfl_xor(r, 2, 64);
                    r += __shfl_xor(r, 4, 64);
                    r += __shfl_xor(r, 8, 64);
                    lrow[qi][j] = lrow[qi][j] * corr[j] + r;
                }
                bool need = (corr[0] < 1.f) || (corr[1] < 1.f) || (corr[2] < 1.f) || (corr[3] < 1.f);
                if (__any((int)need)) {
                    #pragma unroll
                    for (int dt = 0; dt < 4; ++dt)
                        #pragma unroll
                        for (int j = 0; j < 4; ++j)
                            accO[qi][dt][j] *= corr[j];
                }
                #pragma unroll
                for (int kj = 0; kj < 4; ++kj)
                    #pragma unroll
                    for (int j = 0; j < 4; ++j)
                        Plds[wv][(qi * 16 + l4 * 4 + j) * 72 + kj * 16 + l15] = f2bf(ps[kj][j]);
            }
            #pragma unroll
            for (int qi = 0; qi < 2; ++qi) {
                #pragma unroll
                for (int ks = 0; ks < 2; ++ks) {
                    bf16x8 af = *reinterpret_cast<const bf16x8*>(
                        &Plds[wv][(qi * 16 + l15) * 72 + ks * 32 + l4 * 8]);
                    #pragma unroll
                    for (int dt = 0; dt < 4; ++dt) {
                        bf16x8 vf = *reinterpret_cast<const bf16x8*>(
                            &Vt[(dt * 16 + l15) * 72 + ks * 32 + l4 * 8]);
                        accO[qi][dt] = __builtin_amdgcn_mfma_f32_16x16x32_bf16(af, vf, accO[qi][dt], 0, 0, 0);
                    }
                }
            }
        }
        kr0 = nk0; kr1 = nk1; vr0 = nv0; vr1 = nv1;
    }

    #pragma unroll
    for (int qi = 0; qi < 2; ++qi) {
        float inv[4];
        #pragma unroll
        for (int j = 0; j < 4; ++j) inv[j] = 1.f / lrow[qi][j];
        #pragma unroll
        for (int dt = 0; dt < 4; ++dt) {
            #pragma unroll
            for (int j = 0; j < 4; ++j) {
                int crow = n * Cdim + wv * 32 + qi * 16 + l4 * 4 + j;
                ao[(size_t)(R0 + crow) * Ddim + h * DHdim + dt * 16 + l15] =
                    f2bf(accO[qi][dt][j] * inv[j]);
            }
        }
    }
}

// ---------------- global token rows attend to all S keys ----------------
__global__ __launch_bounds__(256) void k_attn_glob(const ushort* __restrict__ qkv,
        const int* __restrict__ glob, const int* __restrict__ amask,
        ushort* __restrict__ ao) {
    int g = blockIdx.x, h = blockIdx.y, b = blockIdx.z;
    __shared__ float sc[Sdim];
    __shared__ float qs[DHdim];
    __shared__ float redm[4], reds[4];
    __shared__ float part[32][DHdim];
    int t = threadIdx.x;
    int qr = glob[g];
    const int R0 = b * Sdim;
    if (t < DHdim)
        qs[t] = bf2f(qkv[(size_t)(R0 + qr) * QKVS + h * DHdim + t]) * 0.125f;
    __syncthreads();
    float lm = -1e30f;
    for (int s0 = t; s0 < Sdim; s0 += 256) {
        const ushort8v* kr = (const ushort8v*)(qkv + (size_t)(R0 + s0) * QKVS + Ddim + h * DHdim);
        float s = 0.f;
        #pragma unroll
        for (int cc = 0; cc < 8; ++cc) {
            ushort8v kv = kr[cc];
            #pragma unroll
            for (int e = 0; e < 8; ++e) s += qs[cc * 8 + e] * bf2f(kv[e]);
        }
        if (amask[b * Sdim + s0] == 0) s = -1e30f;
        sc[s0] = s;
        lm = fmaxf(lm, s);
    }
    #pragma unroll
    for (int o = 32; o; o >>= 1) lm = fmaxf(lm, __shfl_xor(lm, o, 64));
    if ((t & 63) == 0) redm[t >> 6] = lm;
    __syncthreads();
    float mx = fmaxf(fmaxf(redm[0], redm[1]), fmaxf(redm[2], redm[3]));
    float lsum = 0.f;
    for (int s0 = t; s0 < Sdim; s0 += 256) {
        float p = __expf(sc[s0] - mx);
        sc[s0] = p; lsum += p;
    }
    #pragma unroll
    for (int o = 32; o; o >>= 1) lsum += __shfl_xor(lsum, o, 64);
    if ((t & 63) == 0) reds[t >> 6] = lsum;
    __syncthreads();
    float l = reds[0] + reds[1] + reds[2] + reds[3];
    int chunk = t >> 3, dg = t & 7;
    float a[8] = {};
    for (int r = chunk * 64; r < chunk * 64 + 64; ++r) {
        float p = sc[r];
        ushort8v vv = *(const ushort8v*)(qkv + (size_t)(R0 + r) * QKVS + 2 * Ddim + h * DHdim + dg * 8);
        #pragma unroll
        for (int e = 0; e < 8; ++e) a[e] += p * bf2f(vv[e]);
    }
    #pragma unroll
    for (int e = 0; e < 8; ++e) part[chunk][dg * 8 + e] = a[e];
    __syncthreads();
    if (t < DHdim) {
        float o = 0.f;
        #pragma unroll
        for (int c = 0; c < 32; ++c) o += part[c][t];
        ao[(size_t)(R0 + qr) * Ddim + h * DHdim + t] = f2bf(o / l);
    }
}

// ---------------- classification head (256 thr, 2-way k-split) ----------------
__global__ __launch_bounds__(256) void k_head(const float* __restrict__ x,
        const int* __restrict__ glob, const float* __restrict__ Wh,
        const float* __restrict__ bh, const float* __restrict__ Wout,
        const float* __restrict__ bout, float* __restrict__ out) {
    int i = blockIdx.x;
    int b = i / 14, j = i % 14;
    __shared__ float emb[2 * Ddim];
    __shared__ float hp[2][128];
    __shared__ float hid[HIDd];
    int t = threadIdx.x;
    int p = glob[j + 2];
    for (int d = t; d < Ddim; d += 256) {
        emb[d] = x[(long)b * Sdim * Ddim + d];
        emb[Ddim + d] = x[((long)b * Sdim + p) * Ddim + d];
    }
    __syncthreads();
    int nn = t & 127, half = t >> 7;
    float s = 0.f;
    if (nn < HIDd) {
        int k0 = half * Ddim;
        for (int k1 = 0; k1 < Ddim; ++k1) s += emb[k0 + k1] * Wh[(k0 + k1) * HIDd + nn];
    }
    hp[half][nn] = s;
    __syncthreads();
    if (t < HIDd) hid[t] = fmaxf(hp[0][t] + hp[1][t] + bh[t], 0.f);
    __syncthreads();
    if (t < NCLSd) {
        float s2 = bout[t];
        for (int o = 0; o < HIDd; ++o) s2 += hid[o] * Wout[o * NCLSd + t];
        out[i * NCLSd + t] = s2;
    }
}

extern "C" void kernel_launch(void* const* d_in, const int* in_sizes, int n_in,
                              void* d_out, int out_size, void* d_ws, size_t ws_size,
                              hipStream_t stream) {
    const int*   ids   = (const int*)d_in[0];
    const int*   am    = (const int*)d_in[1];
    const float* tok   = (const float*)d_in[2];
    const float* pos   = (const float*)d_in[3];
    const float* lneg  = (const float*)d_in[4];
    const float* lneb  = (const float*)d_in[5];
    const float* Wq    = (const float*)d_in[6];
    const float* bq    = (const float*)d_in[7];
    const float* Wk    = (const float*)d_in[8];
    const float* bk    = (const float*)d_in[9];
    const float* Wv    = (const float*)d_in[10];
    const float* bv    = (const float*)d_in[11];
    const float* Wo    = (const float*)d_in[12];
    const float* bo    = (const float*)d_in[13];
    const float* ln1g  = (const float*)d_in[14];
    const float* ln1b  = (const float*)d_in[15];
    const float* W1    = (const float*)d_in[16];
    const float* b1    = (const float*)d_in[17];
    const float* W2    = (const float*)d_in[18];
    const float* b2    = (const float*)d_in[19];
    const float* ln2g  = (const float*)d_in[20];
    const float* ln2b  = (const float*)d_in[21];
    const float* Wh    = (const float*)d_in[22];
    const float* bh    = (const float*)d_in[23];
    const float* Wout  = (const float*)d_in[24];
    const float* bout  = (const float*)d_in[25];
    float* out = (float*)d_out;

    char* ws = (char*)d_ws;
    const size_t SZ = (size_t)MROWS * Ddim * sizeof(float);
    const size_t HB = SZ / 2;
    size_t off = 0;
    float*  x    = (float*)(ws + off);  off += SZ;
    float*  pr4  = (float*)(ws + off);  off += 4 * SZ;
    ushort* xb   = (ushort*)(ws + off); off += HB;
    ushort* qkvB = (ushort*)(ws + off); off += (size_t)MROWS * QKVS * 2;
    ushort* aoB  = (ushort*)(ws + off); off += HB;
    ushort* hh   = (ushort*)(ws + off); off += (size_t)MROWS * FFdim * 2;
    const size_t WSMALL = (size_t)Ddim * Ddim;
    const size_t WBIG   = (size_t)Ddim * FFdim;
    const size_t WL     = 4 * WSMALL + 2 * WBIG;
    ushort* wts = (ushort*)(ws + off); off += WL * Ldim * 2;
    float* bqkv = (float*)(ws + off);  off += Ldim * QKVS * sizeof(float);
    int* glob = (int*)(ws + off); off += 256;
    int* isg  = (int*)(ws + off);

    k_findsep<<<1, 1024, 0, stream>>>(ids, glob, isg, bq, bk, bv, bqkv);
    k_w2bt_all<<<3456, 256, 0, stream>>>(Wq, Wk, Wv, Wo, W1, W2, wts);
    k_embed<<<MROWS, 64, 0, stream>>>(ids, tok, pos, lneg, lneb, x, xb);

    dim3 gQKV(QKVS / 128, MROWS / 128);
    dim3 gFF(FFdim / 128, MROWS / 128);
    dim3 gSK(Ddim / 128, MROWS / 128, 4);
    dim3 gloc(NCdim, Hdim, Bdim);
    dim3 gglb(Gdim, Hdim, Bdim);

    for (int l = 0; l < Ldim; ++l) {
        ushort* base = wts + l * WL;
        ushort* Wqkvt = base;
        ushort* Wot = base + 3 * WSMALL;
        ushort* W1t = base + 4 * WSMALL;
        ushort* W2t = base + 4 * WSMALL + WBIG;
        k_gemm_bf16<0,1><<<gQKV, 256, 0, stream>>>(xb, Wqkvt, bqkv + l * QKVS, qkvB, MROWS, QKVS, Ddim);
        k_attn_mfma<<<gloc, 256, 0, stream>>>(qkvB, isg, glob, am, aoB);
        k_attn_glob<<<gglb, 256, 0, stream>>>(qkvB, glob, am, aoB);
        k_gemm_splitk<<<gSK, 256, 0, stream>>>(aoB, Wot, pr4, MROWS, Ddim, Ddim, Ddim / 4);
        k_ln_res4<<<MROWS, 64, 0, stream>>>(x, pr4, bo + l * Ddim, ln1g + l * Ddim, ln1b + l * Ddim, xb);
        k_gemm_bf16<1,1><<<gFF, 256, 0, stream>>>(xb, W1t, b1 + l * FFdim, hh, MROWS, FFdim, Ddim);
        k_gemm_splitk<<<gSK, 256, 0, stream>>>(hh, W2t, pr4, MROWS, Ddim, FFdim, FFdim / 4);
        k_ln_res4<<<MROWS, 64, 0, stream>>>(x, pr4, b2 + l * Ddim, ln2g + l * Ddim, ln2b + l * Ddim, xb);
    }
    k_head<<<Bdim * (NSEPd - 2), 256, 0, stream>>>(x, glob, Wh, bh, Wout, bout, out);
}